// Round 4
// baseline (115.280 us; speedup 1.0000x reference)
//
#include <hip/hip_runtime.h>

#define N 4096
#define D 256
#define MARGIN 0.3f
#define BIG 10000.0f

typedef _Float16 f16x8 __attribute__((ext_vector_type(8)));
typedef _Float16 f16x4 __attribute__((ext_vector_type(4)));
typedef float floatx16 __attribute__((ext_vector_type(16)));

__device__ inline void atomicMaxFloatPos(float* a, float v) {
    atomicMax((int*)a, __float_as_int(v));   // valid: all values >= 0
}
__device__ inline void atomicMinFloatPos(float* a, float v) {
    atomicMin((int*)a, __float_as_int(v));
}

// prep v2: convert x -> fp16 (RNE) and write Xf in MFMA-FRAGMENT-SWIZZLED
// layout. For the 32x32x16 f16 MFMA, BOTH operands use the same per-lane
// mapping: lane l holds row = rb*32 + (l&31), k = kb*16 + (l>>5)*8 + j.
// We store element (row, k) of the fp16 matrix at
//   elem[ ((row>>5)*16 + (k>>4))*512 + (((k>>3)&1)*32 + (row&31))*8 + (k&7) ]
// so a wave's whole fragment (rb, kb) is ONE contiguous 1 KB chunk loaded as
// global_load_dwordx4 at base + lane*16 (perfectly coalesced, L2-resident).
// sq comes from the CONVERTED values so the Gram diagonal cancels exactly.
__global__ __launch_bounds__(256) void prep_kernel(const float* __restrict__ x,
                                                   float* __restrict__ sq,
                                                   _Float16* __restrict__ Xf,
                                                   float* ap, float* ang, float* anl) {
    const int wave = threadIdx.x >> 6, lane = threadIdx.x & 63;
    const int row = blockIdx.x * 4 + wave;
    const float4 v = *(const float4*)(x + (size_t)row * D + lane * 4);
    f16x4 h;
    h[0] = (_Float16)v.x; h[1] = (_Float16)v.y;
    h[2] = (_Float16)v.z; h[3] = (_Float16)v.w;
    // k-range of this lane: [4*lane, 4*lane+4) -> kb = lane>>2, hi = (lane>>1)&1,
    // j0 = (lane&1)*4  (contiguous 4 elems within one 8-elem group).
    const int kb = lane >> 2, hi = (lane >> 1) & 1, j0 = (lane & 1) * 4;
    const size_t dst = ((size_t)(row >> 5) * 16 + kb) * 512 + (hi * 32 + (row & 31)) * 8 + j0;
    *(f16x4*)(Xf + dst) = h;
    const float c0 = (float)h[0], c1 = (float)h[1], c2 = (float)h[2], c3 = (float)h[3];
    float s = c0 * c0 + c1 * c1 + c2 * c2 + c3 * c3;
    #pragma unroll
    for (int off = 32; off; off >>= 1) s += __shfl_down(s, off);
    if (lane == 0) sq[row] = s;
    if (threadIdx.x < 4) {
        const int i = blockIdx.x * 4 + threadIdx.x;
        ap[i] = 0.0f; ang[i] = BIG; anl[i] = BIG;
    }
}

// dist v5: NO LDS, NO barriers, NO waitcnt choreography. 4 waves (256 thr)
// per 128x128 tile; wave (wr,wc) owns a 64x64 sub-tile. All MFMA fragments
// are loaded DIRECTLY global->VGPR from the fragment-swizzled Xf (each is a
// coalesced 1 KB dwordx4 at base + lane*16; Xf is 2 MB = L2-resident).
// 16 kb-steps x {4 loads + 4 MFMAs}, fully unrolled - the compiler pipelines
// loads arbitrarily deep and 16 waves/CU of TLP cover L2 latency. Waves 0/1
// share A streams and 0/2 share B streams -> L1 reuse within the block.
// Epilogue: in-register column reduction (anchor = column, valid by symmetry
// of dist); row labels from two __ballot packs; sqi via register + __shfl;
// hi-halves combined with __shfl_xor(32); 6 atomics from lanes 0..31.
__global__ __launch_bounds__(256, 4) void dist_kernel(const _Float16* __restrict__ Xf,
                                                      const int* __restrict__ tgt,
                                                      const float* __restrict__ sq,
                                                      float* __restrict__ dist,
                                                      float* ap, float* ang, float* anl) {
    const int tid  = threadIdx.x;
    const int wv   = tid >> 6;
    const int lane = tid & 63;
    const int row0 = blockIdx.y * 128;
    const int col0 = blockIdx.x * 128;
    const int wr = wv >> 1, wc = wv & 1;

    // Fragment stream bases: row-block rb occupies 16 kb-chunks of 512 elems.
    const int RB0 = blockIdx.y * 4 + wr * 2;        // A row-blocks RB0, RB0+1
    const int CB0 = blockIdx.x * 4 + wc * 2;        // B row-blocks CB0, CB0+1
    const _Float16* pa0 = Xf + (size_t)RB0 * 16 * 512 + lane * 8;
    const _Float16* pa1 = pa0 + 16 * 512;
    const _Float16* pb0 = Xf + (size_t)CB0 * 16 * 512 + lane * 8;
    const _Float16* pb1 = pb0 + 16 * 512;

    // Epilogue scalars prefetched (latency hides under the K-loop).
    const int m0 = lane & 31;
    const int hi = lane >> 5;
    const int rowbase = row0 + wr * 64;
    const int colbase = col0 + wc * 64;
    const int tl = tgt[rowbase + lane];
    const float sq_r = sq[rowbase + lane];
    const unsigned long long pb_0 = __ballot(tl & 1);
    const unsigned long long pb_1 = __ballot(tl & 2);
    const int gc0 = colbase + m0, gc1 = colbase + 32 + m0;
    const int tc0 = tgt[gc0], tc1 = tgt[gc1];
    const float sqc0 = sq[gc0], sqc1 = sq[gc1];

    floatx16 acc[2][2];
    #pragma unroll
    for (int mt = 0; mt < 2; ++mt)
        #pragma unroll
        for (int nt = 0; nt < 2; ++nt)
            #pragma unroll
            for (int r = 0; r < 16; ++r) acc[mt][nt][r] = 0.0f;

    #pragma unroll
    for (int kb = 0; kb < 16; ++kb) {
        const f16x8 a0 = *(const f16x8*)(pa0 + kb * 512);
        const f16x8 a1 = *(const f16x8*)(pa1 + kb * 512);
        const f16x8 b0 = *(const f16x8*)(pb0 + kb * 512);
        const f16x8 b1 = *(const f16x8*)(pb1 + kb * 512);
        acc[0][0] = __builtin_amdgcn_mfma_f32_32x32x16_f16(a0, b0, acc[0][0], 0, 0, 0);
        acc[0][1] = __builtin_amdgcn_mfma_f32_32x32x16_f16(a0, b1, acc[0][1], 0, 0, 0);
        acc[1][0] = __builtin_amdgcn_mfma_f32_32x32x16_f16(a1, b0, acc[1][0], 0, 0, 0);
        acc[1][1] = __builtin_amdgcn_mfma_f32_32x32x16_f16(a1, b1, acc[1][1], 0, 0, 0);
    }

    // ---- Epilogue: d = sqrt(sqi + sqj - 2*dot); nontemporal coalesced global
    // stores; in-register column reduction (anchor = column).
    // C layout: col = lane&31 (+32*nt), row = (r&3) + 8*(r>>2) + 4*hi + 32*mt.
    const int rl_base = 4 * hi;

    float mx0 = 0.0f, mg0 = BIG, ml0 = BIG;
    float mx1 = 0.0f, mg1 = BIG, ml1 = BIG;

    #pragma unroll
    for (int mt = 0; mt < 2; ++mt) {
        #pragma unroll
        for (int r = 0; r < 16; ++r) {
            const int row_l = mt * 32 + (r & 3) + 8 * (r >> 2) + rl_base;
            const int grow  = rowbase + row_l;
            const float sqi = __shfl(sq_r, row_l);
            const float d0 = sqrtf(fmaxf(sqi + sqc0 - 2.0f * acc[mt][0][r], 0.0f));
            const float d1 = sqrtf(fmaxf(sqi + sqc1 - 2.0f * acc[mt][1][r], 0.0f));
            __builtin_nontemporal_store(d0, dist + (size_t)grow * N + gc0);
            __builtin_nontemporal_store(d1, dist + (size_t)grow * N + gc1);
            const int tr = (int)((pb_0 >> row_l) & 1) | ((int)((pb_1 >> row_l) & 1) << 1);
            mx0 = fmaxf(mx0, (tr == tc0) ? d0 : 0.0f);
            mg0 = fminf(mg0, (tr >  tc0) ? d0 : BIG);
            ml0 = fminf(ml0, (tr <  tc0) ? d0 : BIG);
            mx1 = fmaxf(mx1, (tr == tc1) ? d1 : 0.0f);
            mg1 = fminf(mg1, (tr >  tc1) ? d1 : BIG);
            ml1 = fminf(ml1, (tr <  tc1) ? d1 : BIG);
        }
    }
    // combine the two hi-halves (each reduced 32 of the 64 rows)
    mx0 = fmaxf(mx0, __shfl_xor(mx0, 32));
    mg0 = fminf(mg0, __shfl_xor(mg0, 32));
    ml0 = fminf(ml0, __shfl_xor(ml0, 32));
    mx1 = fmaxf(mx1, __shfl_xor(mx1, 32));
    mg1 = fminf(mg1, __shfl_xor(mg1, 32));
    ml1 = fminf(ml1, __shfl_xor(ml1, 32));

    if (hi == 0) {
        atomicMaxFloatPos(&ap[gc0],  mx0);
        atomicMinFloatPos(&ang[gc0], mg0);
        atomicMinFloatPos(&anl[gc0], ml0);
        atomicMaxFloatPos(&ap[gc1],  mx1);
        atomicMinFloatPos(&ang[gc1], mg1);
        atomicMinFloatPos(&anl[gc1], ml1);
    }
}

// One block: histogram (packed wave reduce), then loss/cnt, write outputs.
__global__ __launch_bounds__(1024) void finish_kernel(const float* __restrict__ ap,
                                                      const float* __restrict__ ang,
                                                      const float* __restrict__ anl,
                                                      const int* __restrict__ tgt,
                                                      float* __restrict__ out) {
    __shared__ int hist[4];
    __shared__ unsigned hsum[2][16];
    __shared__ float wsum[16];
    __shared__ int wcnt[16];
    const int tid = threadIdx.x, lane = tid & 63, wv = tid >> 6;

    const int4 t4 = *(const int4*)&tgt[tid * 4];
    int c[4] = {0, 0, 0, 0};
    c[t4.x & 3]++; c[t4.y & 3]++; c[t4.z & 3]++; c[t4.w & 3]++;
    unsigned p01 = (unsigned)c[0] | ((unsigned)c[1] << 16);
    unsigned p23 = (unsigned)c[2] | ((unsigned)c[3] << 16);
    #pragma unroll
    for (int off = 32; off; off >>= 1) {
        p01 += __shfl_down(p01, off);
        p23 += __shfl_down(p23, off);
    }
    if (lane == 0) { hsum[0][wv] = p01; hsum[1][wv] = p23; }
    __syncthreads();
    if (tid == 0) {
        unsigned a = 0, b = 0;
        for (int i = 0; i < 16; ++i) { a += hsum[0][i]; b += hsum[1][i]; }
        hist[0] = a & 0xFFFF; hist[1] = a >> 16;
        hist[2] = b & 0xFFFF; hist[3] = b >> 16;
    }
    __syncthreads();

    float term = 0.0f; int cc = 0;
    const int lab[4] = {t4.x & 3, t4.y & 3, t4.z & 3, t4.w & 3};
    #pragma unroll
    for (int j = 0; j < 4; ++j) {
        const int i = tid * 4 + j;
        term += fmaxf(ap[i] - fabsf(ang[i] - anl[i]) + MARGIN, 0.0f);
        cc += (hist[lab[j]] == 1) ? 1 : 0;
    }
    #pragma unroll
    for (int off = 32; off; off >>= 1) {
        term += __shfl_down(term, off);
        cc   += __shfl_down(cc, off);
    }
    if (lane == 0) { wsum[wv] = term; wcnt[wv] = cc; }
    __syncthreads();
    if (tid == 0) {
        float ls = 0.0f; int cs = 0;
        for (int i = 0; i < 16; ++i) { ls += wsum[i]; cs += wcnt[i]; }
        out[0] = ls * (1.0f / N);
        out[1 + (size_t)N * N] = (float)cs;
    }
}

extern "C" void kernel_launch(void* const* d_in, const int* in_sizes, int n_in,
                              void* d_out, int out_size, void* d_ws, size_t ws_size,
                              hipStream_t stream) {
    const float* x   = (const float*)d_in[0];
    const int*   tgt = (const int*)d_in[1];
    float* out = (float*)d_out;
    char*  ws  = (char*)d_ws;

    _Float16* Xf  = (_Float16*)ws;                    // 2 MiB, 16B-aligned
    float*    sq  = (float*)(ws + 2097152);
    float*    ap  = sq + 4096;
    float*    ang = sq + 8192;
    float*    anl = sq + 12288;

    prep_kernel<<<N / 4, 256, 0, stream>>>(x, sq, Xf, ap, ang, anl);
    dim3 grid(N / 128, N / 128);
    dist_kernel<<<grid, 256, 0, stream>>>(Xf, tgt, sq, out + 1, ap, ang, anl);
    finish_kernel<<<1, 1024, 0, stream>>>(ap, ang, anl, tgt, out);
}

// Round 5
// 108.870 us; speedup vs baseline: 1.0589x; 1.0589x over previous
//
#include <hip/hip_runtime.h>

#define N 4096
#define D 256
#define MARGIN 0.3f
#define BIG 10000.0f

typedef _Float16 f16x8 __attribute__((ext_vector_type(8)));
typedef _Float16 f16x4 __attribute__((ext_vector_type(4)));
typedef float floatx16 __attribute__((ext_vector_type(16)));

__device__ inline void atomicMaxFloatPos(float* a, float v) {
    atomicMax((int*)a, __float_as_int(v));   // valid: all values >= 0
}
__device__ inline void atomicMinFloatPos(float* a, float v) {
    atomicMin((int*)a, __float_as_int(v));
}

// async 16B global -> LDS (wave-uniform LDS base + lane*16)
__device__ inline void gl_lds16(const void* g, void* l) {
    __builtin_amdgcn_global_load_lds(
        (const __attribute__((address_space(1))) unsigned int*)g,
        (__attribute__((address_space(3))) unsigned int*)l, 16, 0, 0);
}

// Wave per row: convert x -> fp16 Xf (RNE, row-major), sq from the CONVERTED
// values (so the Gram diagonal cancels exactly), init ap/ang/anl.
__global__ __launch_bounds__(256) void prep_kernel(const float* __restrict__ x,
                                                   float* __restrict__ sq,
                                                   _Float16* __restrict__ Xf,
                                                   float* ap, float* ang, float* anl) {
    const int wave = threadIdx.x >> 6, lane = threadIdx.x & 63;
    const int row = blockIdx.x * 4 + wave;
    const float4 v = *(const float4*)(x + (size_t)row * D + lane * 4);
    f16x4 h;
    h[0] = (_Float16)v.x; h[1] = (_Float16)v.y;
    h[2] = (_Float16)v.z; h[3] = (_Float16)v.w;
    *(f16x4*)(Xf + (size_t)row * D + lane * 4) = h;
    const float c0 = (float)h[0], c1 = (float)h[1], c2 = (float)h[2], c3 = (float)h[3];
    float s = c0 * c0 + c1 * c1 + c2 * c2 + c3 * c3;
    #pragma unroll
    for (int off = 32; off; off >>= 1) s += __shfl_down(s, off);
    if (lane == 0) sq[row] = s;
    if (threadIdx.x < 4) {
        const int i = blockIdx.x * 4 + threadIdx.x;
        ap[i] = 0.0f; ang[i] = BIG; anl[i] = BIG;
    }
}

// dist v6: 8 waves (512 thr) per 256x256 tile, double-buffered 128 KB LDS,
// counted-vmcnt pipeline (T3/T4): stage s+1's DMA is issued BEFORE waiting
// on stage s; the wait is vmcnt(8) (stage s+1's 8 loads stay in flight),
// vmcnt(0) only on the last stage. The K-loop contains NO other VMEM ops,
// so the counts are exact. Staging totals 67 MB chip-wide (half of v4).
// LDS: per buffer, A panel 256 rows x 64 fp16 (128 B rows) at 0, B panel at
// +16384 elems; 16B quad l of row r stored at phys quad l ^ (r&7) (proven
// conflict-free b128 scheme). DMA: wave w<4 stages A rows w*64..w*64+63,
// w>=4 stages B rows (w-4)*64..+63 (8 instrs x 1 KB each).
// Wave (wr,wc) = (w>>2, w&3) owns a 128x64 sub-tile -> acc[4][2] floatx16.
// Epilogue: NO LDS. anchor = column (valid by symmetry); row labels for the
// 128 rows from 4 __ballot packs; sqi via 2 registers + __shfl; hi-halves
// combined with __shfl_xor(32); 6 atomics from lanes 0..31.
__global__ __launch_bounds__(512, 2) void dist_kernel(const _Float16* __restrict__ Xf,
                                                      const int* __restrict__ tgt,
                                                      const float* __restrict__ sq,
                                                      float* __restrict__ dist,
                                                      float* ap, float* ang, float* anl) {
    __shared__ _Float16 lds[65536];         // 128 KiB: 2 buffers x (A 32K + B 32K)

    const int tid  = threadIdx.x;
    const int wv   = tid >> 6;              // 0..7
    const int lane = tid & 63;
    const int row0 = blockIdx.y * 256;
    const int col0 = blockIdx.x * 256;
    const int wr = wv >> 2, wc = wv & 3;

    // DMA mapping: instr d of wave wv covers panel rows ((wv&3)*64 + d*8 ..+7).
    // lane: g = lane>>3 (row in 8-group), p = lane&7 (phys quad); fetch
    // logical quad lq = p ^ g (row&7 == g since row-base is a multiple of 8).
    const int g = lane >> 3, p = lane & 7, lq = p ^ g;
    const int base_row = (wv < 4 ? row0 : col0) + (wv & 3) * 64 + g;
    const _Float16* src0 = Xf + (size_t)base_row * D + lq * 8;
    const int dstoff = ((wv & 4) ? 16384 : 0) + (wv & 3) * 4096;  // elems

    const int m0 = lane & 31;
    const int hi = lane >> 5;
    const int sw = m0 & 7;                   // frag swizzle key

    floatx16 acc[4][2];
    #pragma unroll
    for (int mt = 0; mt < 4; ++mt)
        #pragma unroll
        for (int nt = 0; nt < 2; ++nt)
            #pragma unroll
            for (int r = 0; r < 16; ++r) acc[mt][nt][r] = 0.0f;

    // ---- stage DMA issue: 8 x gl_lds16 into buffer (s&1) ----
    #define ISSUE_STAGE(s)                                                        \
    do {                                                                          \
        _Float16* buf_ = lds + ((s) & 1) * 32768;                                 \
        const int k0_ = (s) * 64;                                                 \
        _Pragma("unroll")                                                         \
        for (int d = 0; d < 8; ++d)                                               \
            gl_lds16(src0 + (size_t)d * 8 * D + k0_, buf_ + dstoff + d * 512);    \
    } while (0)

    ISSUE_STAGE(0);

    #pragma unroll
    for (int s = 0; s < 4; ++s) {
        if (s < 3) ISSUE_STAGE(s + 1);       // keep DMA engine busy across the wait
        if (s < 3) { __asm__ volatile("s_waitcnt vmcnt(8)" ::: "memory"); }
        else       { __asm__ volatile("s_waitcnt vmcnt(0)" ::: "memory"); }
        __builtin_amdgcn_s_barrier();        // all waves' stage-s data in LDS
        __asm__ volatile("" ::: "memory");

        const _Float16* buf   = lds + (s & 1) * 32768;
        const _Float16* Abase = buf + ((size_t)wr * 8192 + m0 * 64);
        const _Float16* Bbase = buf + 16384 + ((size_t)wc * 4096 + m0 * 64);

        __builtin_amdgcn_s_setprio(1);
        #pragma unroll
        for (int kb = 0; kb < 4; ++kb) {
            const int po = (((kb * 2 + hi) ^ sw) << 3);
            f16x8 b0 = *(const f16x8*)(Bbase + po);
            f16x8 b1 = *(const f16x8*)(Bbase + 2048 + po);
            #pragma unroll
            for (int mt = 0; mt < 4; ++mt) {
                f16x8 a = *(const f16x8*)(Abase + mt * 2048 + po);
                acc[mt][0] = __builtin_amdgcn_mfma_f32_32x32x16_f16(a, b0, acc[mt][0], 0, 0, 0);
                acc[mt][1] = __builtin_amdgcn_mfma_f32_32x32x16_f16(a, b1, acc[mt][1], 0, 0, 0);
            }
        }
        __builtin_amdgcn_s_setprio(0);

        if (s < 2) {                          // buf (s&1) will be overwritten by
            __asm__ volatile("" ::: "memory");//  ISSUE_STAGE(s+2) next iteration
            __builtin_amdgcn_s_barrier();     //  -> all waves' reads must be done
            __asm__ volatile("" ::: "memory");
        }
    }
    #undef ISSUE_STAGE

    // ---- Epilogue: d = sqrt(sqi + sqj - 2*dot); nontemporal coalesced global
    // stores; in-register column reduction (anchor = column).
    // C layout: col = lane&31 (+32*nt), row = (r&3) + 8*(r>>2) + 4*hi + 32*mt.
    const int rowA    = row0 + wr * 128;
    const int colbase = col0 + wc * 64;
    const int tl0 = tgt[rowA + lane];
    const int tl1 = tgt[rowA + 64 + lane];
    const float sqr0 = sq[rowA + lane];
    const float sqr1 = sq[rowA + 64 + lane];
    const unsigned long long pa0 = __ballot(tl0 & 1), pa1 = __ballot(tl0 & 2);
    const unsigned long long pb0 = __ballot(tl1 & 1), pb1 = __ballot(tl1 & 2);
    const int gc0 = colbase + m0, gc1 = colbase + 32 + m0;
    const int tc0 = tgt[gc0], tc1 = tgt[gc1];
    const float sqc0 = sq[gc0], sqc1 = sq[gc1];
    const int rl_base = 4 * hi;

    float mx0 = 0.0f, mg0 = BIG, ml0 = BIG;
    float mx1 = 0.0f, mg1 = BIG, ml1 = BIG;

    #pragma unroll
    for (int mt = 0; mt < 4; ++mt) {
        #pragma unroll
        for (int r = 0; r < 16; ++r) {
            const int row_l = mt * 32 + (r & 3) + 8 * (r >> 2) + rl_base;  // 0..127
            const int rl = row_l & 63;
            const int grow = rowA + row_l;
            const float sqi = __shfl(mt < 2 ? sqr0 : sqr1, rl);
            const float d0 = sqrtf(fmaxf(sqi + sqc0 - 2.0f * acc[mt][0][r], 0.0f));
            const float d1 = sqrtf(fmaxf(sqi + sqc1 - 2.0f * acc[mt][1][r], 0.0f));
            __builtin_nontemporal_store(d0, dist + (size_t)grow * N + gc0);
            __builtin_nontemporal_store(d1, dist + (size_t)grow * N + gc1);
            const unsigned long long q0 = (mt < 2 ? pa0 : pb0);
            const unsigned long long q1 = (mt < 2 ? pa1 : pb1);
            const int tr = (int)((q0 >> rl) & 1) | ((int)((q1 >> rl) & 1) << 1);
            mx0 = fmaxf(mx0, (tr == tc0) ? d0 : 0.0f);
            mg0 = fminf(mg0, (tr >  tc0) ? d0 : BIG);
            ml0 = fminf(ml0, (tr <  tc0) ? d0 : BIG);
            mx1 = fmaxf(mx1, (tr == tc1) ? d1 : 0.0f);
            mg1 = fminf(mg1, (tr >  tc1) ? d1 : BIG);
            ml1 = fminf(ml1, (tr <  tc1) ? d1 : BIG);
        }
    }
    // combine the two hi-halves (each reduced 64 of the 128 rows)
    mx0 = fmaxf(mx0, __shfl_xor(mx0, 32));
    mg0 = fminf(mg0, __shfl_xor(mg0, 32));
    ml0 = fminf(ml0, __shfl_xor(ml0, 32));
    mx1 = fmaxf(mx1, __shfl_xor(mx1, 32));
    mg1 = fminf(mg1, __shfl_xor(mg1, 32));
    ml1 = fminf(ml1, __shfl_xor(ml1, 32));

    if (hi == 0) {
        atomicMaxFloatPos(&ap[gc0],  mx0);
        atomicMinFloatPos(&ang[gc0], mg0);
        atomicMinFloatPos(&anl[gc0], ml0);
        atomicMaxFloatPos(&ap[gc1],  mx1);
        atomicMinFloatPos(&ang[gc1], mg1);
        atomicMinFloatPos(&anl[gc1], ml1);
    }
}

// One block: histogram (packed wave reduce), then loss/cnt, write outputs.
__global__ __launch_bounds__(1024) void finish_kernel(const float* __restrict__ ap,
                                                      const float* __restrict__ ang,
                                                      const float* __restrict__ anl,
                                                      const int* __restrict__ tgt,
                                                      float* __restrict__ out) {
    __shared__ int hist[4];
    __shared__ unsigned hsum[2][16];
    __shared__ float wsum[16];
    __shared__ int wcnt[16];
    const int tid = threadIdx.x, lane = tid & 63, wv = tid >> 6;

    const int4 t4 = *(const int4*)&tgt[tid * 4];
    int c[4] = {0, 0, 0, 0};
    c[t4.x & 3]++; c[t4.y & 3]++; c[t4.z & 3]++; c[t4.w & 3]++;
    unsigned p01 = (unsigned)c[0] | ((unsigned)c[1] << 16);
    unsigned p23 = (unsigned)c[2] | ((unsigned)c[3] << 16);
    #pragma unroll
    for (int off = 32; off; off >>= 1) {
        p01 += __shfl_down(p01, off);
        p23 += __shfl_down(p23, off);
    }
    if (lane == 0) { hsum[0][wv] = p01; hsum[1][wv] = p23; }
    __syncthreads();
    if (tid == 0) {
        unsigned a = 0, b = 0;
        for (int i = 0; i < 16; ++i) { a += hsum[0][i]; b += hsum[1][i]; }
        hist[0] = a & 0xFFFF; hist[1] = a >> 16;
        hist[2] = b & 0xFFFF; hist[3] = b >> 16;
    }
    __syncthreads();

    float term = 0.0f; int cc = 0;
    const int lab[4] = {t4.x & 3, t4.y & 3, t4.z & 3, t4.w & 3};
    #pragma unroll
    for (int j = 0; j < 4; ++j) {
        const int i = tid * 4 + j;
        term += fmaxf(ap[i] - fabsf(ang[i] - anl[i]) + MARGIN, 0.0f);
        cc += (hist[lab[j]] == 1) ? 1 : 0;
    }
    #pragma unroll
    for (int off = 32; off; off >>= 1) {
        term += __shfl_down(term, off);
        cc   += __shfl_down(cc, off);
    }
    if (lane == 0) { wsum[wv] = term; wcnt[wv] = cc; }
    __syncthreads();
    if (tid == 0) {
        float ls = 0.0f; int cs = 0;
        for (int i = 0; i < 16; ++i) { ls += wsum[i]; cs += wcnt[i]; }
        out[0] = ls * (1.0f / N);
        out[1 + (size_t)N * N] = (float)cs;
    }
}

extern "C" void kernel_launch(void* const* d_in, const int* in_sizes, int n_in,
                              void* d_out, int out_size, void* d_ws, size_t ws_size,
                              hipStream_t stream) {
    const float* x   = (const float*)d_in[0];
    const int*   tgt = (const int*)d_in[1];
    float* out = (float*)d_out;
    char*  ws  = (char*)d_ws;

    _Float16* Xf  = (_Float16*)ws;                    // 2 MiB, 16B-aligned
    float*    sq  = (float*)(ws + 2097152);
    float*    ap  = sq + 4096;
    float*    ang = sq + 8192;
    float*    anl = sq + 12288;

    prep_kernel<<<N / 4, 256, 0, stream>>>(x, sq, Xf, ap, ang, anl);
    dim3 grid(N / 256, N / 256);
    dist_kernel<<<grid, 512, 0, stream>>>(Xf, tgt, sq, out + 1, ap, ang, anl);
    finish_kernel<<<1, 1024, 0, stream>>>(ap, ang, anl, tgt, out);
}